// Round 8
// baseline (305.355 us; speedup 1.0000x reference)
//
#include <hip/hip_runtime.h>
#include <math.h>

// ---------------- MS-SSIM on MI355X, round 10 ----------------
// Async pipeline via the SUPPORTED path: __builtin_amdgcn_global_load_lds
// (no destination registers -> no regalloc hazards; round 9's register-DMA
// aperture fault is structurally impossible). Per-wave LDS row cache
// [2 buf][5 rows][2 imgs][132 floats], 20 LDS-DMA ops per 5-row batch,
// double-buffered with counted s_waitcnt vmcnt(20) + sched_barrier(0).
// Halo read directly from LDS (no shuffles, lanes independent); per-pair
// column masks + row mask at consume. 1-wave blocks (no barriers),
// 15 waves/CU LDS-limited.

typedef float f2 __attribute__((ext_vector_type(2)));

#if __has_builtin(__builtin_elementwise_fma)
static __device__ __forceinline__ f2 vfma(f2 a, f2 b, f2 c) {
    return __builtin_elementwise_fma(a, b, c);
}
#else
static __device__ __forceinline__ f2 vfma(f2 a, f2 b, f2 c) {
    f2 d; d.x = __builtin_fmaf(a.x, b.x, c.x); d.y = __builtin_fmaf(a.y, b.y, c.y);
    return d;
}
#endif

typedef __attribute__((address_space(1))) void gv_t;   // global
typedef __attribute__((address_space(3))) void lv_t;   // LDS

// async global->LDS, 4B/lane: LDS[dest + 4*lane] = *(src_lane). dest uniform.
static __device__ __forceinline__ void gl_lds(const float* g, float* l) {
    __builtin_amdgcn_global_load_lds((gv_t*)g, (lv_t*)l, 4, 0, 0);
}

#define WAITVM(N) do { \
    asm volatile("s_waitcnt vmcnt(" #N ")" ::: "memory"); \
    __builtin_amdgcn_sched_barrier(0); \
} while (0)

#define C1F 0.0001f
#define C2F 0.0009f
// normalized Gaussian, WIN=5, sigma=1.5
#define GW0f 0.12007838f
#define GW1f 0.23388060f
#define GW2f 0.29208204f

// Horizontal 5-tap conv for cols (c0, c0+1) from VL=(c0-2,c0-1),
// V01=(c0,c0+1), VR=(c0+2,c0+3)
#define HCONV(DST, VL, V01, VR) do { \
    const f2 t1_ = (VL) + (VR); \
    f2 mid_; mid_.x = (VL).y + (V01).y; mid_.y = (V01).x + (VR).x; \
    (DST) = vfma(G1v, mid_, vfma(G0v, t1_, G2v * (V01))); \
} while (0)

// Vertical 5-tap conv over rolling window slots (static indices).
#define VCONV(OUT, WN, S0,S1,S2,S3,S4) do { \
    const f2 t_ = WN[S0] + WN[S4]; \
    const f2 u_ = WN[S1] + WN[S3]; \
    (OUT) = vfma(G1v, u_, vfma(G0v, t_, G2v * WN[S2])); \
} while (0)

// Issue the 20 LDS-DMA ops (5 rows x 2 imgs x 2 halves) of batch T into buf B.
// LDS floats [2..65] <- row[clamp(base-2+lane)], [66..129] <- row[clamp(base+62+lane)]
#define LOADB(T, B) do { \
    _Pragma("unroll") \
    for (int k_ = 0; k_ < 5; ++k_) { \
        const int r_ = y0 + (T) * 5 + k_ - 2; \
        const int rc_ = min(max(r_, 0), H - 1); \
        const float* r1_ = p1 + (size_t)rc_ * W; \
        const float* r2_ = p2 + (size_t)rc_ * W; \
        gl_lds(r1_ + col1, &lds[B][k_][0][2]); \
        gl_lds(r1_ + col2, &lds[B][k_][0][66]); \
        gl_lds(r2_ + col1, &lds[B][k_][1][2]); \
        gl_lds(r2_ + col2, &lds[B][k_][1][66]); \
    } \
} while (0)

// One row step. I = step index (compile-time), K = I%5 = row slot in buf B.
// S0..S4 = window slots of rows I-4..I. LDS float f <-> col base-4+f, so
// lane reads XL at 2*lane, X01 at 2*lane+2, XR at 2*lane+4 (pads at ends
// feed only non-output lanes 0/63, masked by select).
#define STEP(I, K, B, S0,S1,S2,S3,S4) do { \
    const int r = y0 + (I) - 2; \
    const float rv = ((unsigned)r < (unsigned)H) ? 1.f : 0.f; \
    const f2 mVv = {rv, rv}; \
    const f2 mLVv = mLv * mVv; \
    const f2 mCVv = mCv * mVv; \
    const f2 mRVv = mRv * mVv; \
    const f2 XL  = *(const f2*)&lds[B][K][0][2 * lane]     * mLVv; \
    const f2 X01 = *(const f2*)&lds[B][K][0][2 * lane + 2] * mCVv; \
    const f2 XR  = *(const f2*)&lds[B][K][0][2 * lane + 4] * mRVv; \
    const f2 ZL  = *(const f2*)&lds[B][K][1][2 * lane]     * mLVv; \
    const f2 Z01 = *(const f2*)&lds[B][K][1][2 * lane + 2] * mCVv; \
    const f2 ZR  = *(const f2*)&lds[B][K][1][2 * lane + 4] * mRVv; \
    const f2 QL = vfma(ZL,  ZL,  XL  * XL); \
    const f2 QC = vfma(Z01, Z01, X01 * X01); \
    const f2 QR = vfma(ZR,  ZR,  XR  * XR); \
    const f2 PL = XL  * ZL; \
    const f2 PC = X01 * Z01; \
    const f2 PR = XR  * ZR; \
    HCONV(wa[(S4)], XL, X01, XR); \
    HCONV(wb[(S4)], ZL, Z01, ZR); \
    HCONV(wq[(S4)], QL, QC,  QR); \
    HCONV(wp[(S4)], PL, PC,  PR); \
    if ((I) >= 4) { \
        f2 Av, Bv, Qv, Pv; \
        VCONV(Av, wa, S0,S1,S2,S3,S4); \
        VCONV(Bv, wb, S0,S1,S2,S3,S4); \
        VCONV(Qv, wq, S0,S1,S2,S3,S4); \
        VCONV(Pv, wp, S0,S1,S2,S3,S4); \
        const f2 ABv   = Av * Bv; \
        const f2 A2B2v = vfma(Bv, Bv, Av * Av); \
        const f2 S12v  = vfma(TWOv, Pv - ABv, C2v); \
        const f2 SDENv = (Qv - A2B2v) + C2v; \
        const f2 D1v   = A2B2v + C1v; \
        const f2 N1v   = vfma(TWOv, ABv, C1v); \
        const f2 DENv  = D1v * SDENv; \
        f2 RDv; \
        RDv.x = __builtin_amdgcn_rcpf(DENv.x); \
        RDv.y = __builtin_amdgcn_rcpf(DENv.y); \
        const f2 SSv = N1v * S12v * RDv; \
        const f2 CCv = S12v * D1v * RDv; \
        ACCS += vout ? SSv : ZEROv; \
        ACCC += vout ? CCv : ZEROv; \
    } \
    { \
        const bool pcond = (TROWS == 1) ? ((I) == 2 && (y0 & 1)) \
                          : (((I) & 1) && (I) >= 3 && (I) <= TROWS + 1); \
        if (q1 && pcond && vout) { \
            const f2 sx_ = X01 + PX; \
            const f2 sz_ = Z01 + PZ; \
            const size_t po_ = (size_t)(r >> 1) * WP + (c0 >> 1); \
            q1[po_] = (sx_.x + sx_.y) * 0.25f; \
            q2[po_] = (sz_.x + sz_.y) * 0.25f; \
        } \
    } \
    PX = X01; PZ = Z01; \
} while (0)

#define BATCH(T, B) do { \
    STEP((T)*5+0, 0, B, 1,2,3,4,0); \
    STEP((T)*5+1, 1, B, 2,3,4,0,1); \
    STEP((T)*5+2, 2, B, 3,4,0,1,2); \
    STEP((T)*5+3, 3, B, 4,0,1,2,3); \
    STEP((T)*5+4, 4, B, 0,1,2,3,4); \
} while (0)

template<int TROWS, int H, int W, int SX>
__global__ __launch_bounds__(64)
void ssim_level_kernel(const float* __restrict__ img1,
                       const float* __restrict__ img2,
                       float* __restrict__ pool1,
                       float* __restrict__ pool2,
                       double* __restrict__ block_out)
{
    constexpr int SY = H / TROWS;
    constexpr int spp = SX * SY;
    constexpr int ITERS = TROWS + 4;
    constexpr int NB = ITERS / 5;
    static_assert(ITERS % 5 == 0, "TROWS+4 must be divisible by 5");
    static_assert(NB == 1 || NB == 4, "pipeline written for NB in {1,4}");
    constexpr int WP = W >> 1;

    __shared__ float lds[2][5][2][132];    // 10560 B, per-wave private

    const int lane = threadIdx.x;          // 1-wave blocks: 0..63
    const int w    = blockIdx.x;

    const int plane = w / spp;
    const int rem   = w - plane * spp;
    const int sy    = rem / SX;
    const int sx    = rem - sy * SX;

    const int base = sx * 124;
    const int y0   = sy * TROWS;
    const int c0   = base - 2 + 2 * lane;          // lane owns cols c0, c0+1

    // per-pair validity (pairs are uniformly valid/invalid: c0 even, W even)
    const bool okL = (c0 >= 2) && (c0 <= W);       // cols c0-2, c0-1
    const bool okC = (c0 >= 0) && (c0 <= W - 2);   // cols c0,   c0+1
    const bool okR = (c0 <= W - 4);                // cols c0+2, c0+3
    const bool vout = okC && lane >= 1 && lane <= 62;
    const f2 mLv = {okL ? 1.f : 0.f, okL ? 1.f : 0.f};
    const f2 mCv = {okC ? 1.f : 0.f, okC ? 1.f : 0.f};
    const f2 mRv = {okR ? 1.f : 0.f, okR ? 1.f : 0.f};
    const f2 ZEROv = {0.f, 0.f};

    // per-lane clamped source columns for the two staging halves
    const int col1 = min(max(base - 2 + lane, 0), W - 1);
    const int col2 = min(max(base + 62 + lane, 0), W - 1);

    const float* p1 = img1 + (size_t)plane * (H * W);
    const float* p2 = img2 + (size_t)plane * (H * W);
    float* q1 = pool1 ? pool1 + (size_t)plane * (H >> 1) * WP : nullptr;
    float* q2 = pool2 ? pool2 + (size_t)plane * (H >> 1) * WP : nullptr;

    const f2 G0v  = {GW0f, GW0f};
    const f2 G1v  = {GW1f, GW1f};
    const f2 G2v  = {GW2f, GW2f};
    const f2 C1v  = {C1F, C1F};
    const f2 C2v  = {C2F, C2F};
    const f2 TWOv = {2.f, 2.f};

    f2 wa[5], wb[5], wq[5], wp[5];
    f2 PX = {0.f, 0.f}, PZ = {0.f, 0.f};
    f2 ACCS = {0.f, 0.f}, ACCC = {0.f, 0.f};

    if constexpr (NB == 4) {
        LOADB(0, 0);
        LOADB(1, 1);
        WAITVM(20);                 // batch 0 in LDS; batch 1 in flight
        BATCH(0, 0);
        LOADB(2, 0);
        WAITVM(20);                 // batch 1 ready; batch 2 in flight
        BATCH(1, 1);
        LOADB(3, 1);
        WAITVM(20);                 // batch 2 ready; batch 3 in flight
        BATCH(2, 0);
        WAITVM(0);                  // batch 3 ready
        BATCH(3, 1);
    } else {
        LOADB(0, 0);
        WAITVM(0);
        BATCH(0, 0);
    }

    float accs = ACCS.x + ACCS.y;
    float accc = ACCC.x + ACCC.y;
    #pragma unroll
    for (int o = 32; o > 0; o >>= 1) {
        accs += __shfl_down(accs, o, 64);
        accc += __shfl_down(accc, o, 64);
    }
    if (lane == 0) {
        block_out[2 * (size_t)w]     = (double)accs;
        block_out[2 * (size_t)w + 1] = (double)accc;
    }
}

// per-level block counts / slot offsets (one double2 slot per 1-wave block)
static constexpr int NBLK[5] = {15360, 4608, 1536, 6144, 3072};
static constexpr int BOFF[5] = {0, 15360, 19968, 21504, 27648};  // total 30720

__global__ __launch_bounds__(1024)
void ssim_final_kernel(const double* __restrict__ bsum, float* __restrict__ out)
{
    __shared__ double partial[16][2];
    __shared__ double lvl[5][2];
    const double npx[5] = {96.0*512*512, 96.0*256*256, 96.0*128*128,
                           96.0*64*64,   96.0*32*32};
    const int tid = threadIdx.x, lane = tid & 63, wv = tid >> 6;

    for (int l = 0; l < 5; ++l) {
        double s = 0.0, c = 0.0;
        for (int k = tid; k < NBLK[l]; k += 1024) {
            s += bsum[2 * (size_t)(BOFF[l] + k)];
            c += bsum[2 * (size_t)(BOFF[l] + k) + 1];
        }
        #pragma unroll
        for (int o = 32; o > 0; o >>= 1) {
            s += __shfl_down(s, o, 64);
            c += __shfl_down(c, o, 64);
        }
        if (lane == 0) { partial[wv][0] = s; partial[wv][1] = c; }
        __syncthreads();
        if (tid == 0) {
            double ts = 0.0, tc = 0.0;
            for (int k = 0; k < 16; ++k) { ts += partial[k][0]; tc += partial[k][1]; }
            lvl[l][0] = ts / npx[l];
            lvl[l][1] = tc / npx[l];
        }
        __syncthreads();
    }
    if (tid == 0) {
        const double wgt[5] = {0.0448, 0.2856, 0.3001, 0.2363, 0.1333};
        double ssim4 = (lvl[4][0] + 1.0) * 0.5;
        double P = pow(ssim4, wgt[4]);
        double r = pow((lvl[0][1] + 1.0) * 0.5, wgt[0]) *
                   pow((lvl[1][1] + 1.0) * 0.5, wgt[1]) *
                   pow((lvl[2][1] + 1.0) * 0.5, wgt[2]) *
                   pow((lvl[3][1] + 1.0) * 0.5, wgt[3]);
        r *= P * P * P * P;
        out[0] = (float)r;
    }
}

extern "C" void kernel_launch(void* const* d_in, const int* in_sizes, int n_in,
                              void* d_out, int out_size, void* d_ws, size_t ws_size,
                              hipStream_t stream)
{
    const float* img1 = (const float*)d_in[0];
    const float* img2 = (const float*)d_in[1];
    float* out = (float*)d_out;

    char* ws = (char*)d_ws;
    double* wsum = (double*)ws;                 // 30720 double2 slots (492 KB)
    size_t off = 524288;                        // pooled arrays after 512 KB
    const size_t P = 96;
    float* l1a = (float*)(ws + off); off += P * 256 * 256 * sizeof(float);
    float* l1b = (float*)(ws + off); off += P * 256 * 256 * sizeof(float);
    float* l2a = (float*)(ws + off); off += P * 128 * 128 * sizeof(float);
    float* l2b = (float*)(ws + off); off += P * 128 * 128 * sizeof(float);
    float* l3a = (float*)(ws + off); off += P * 64 * 64 * sizeof(float);
    float* l3b = (float*)(ws + off); off += P * 64 * 64 * sizeof(float);
    float* l4a = (float*)(ws + off); off += P * 32 * 32 * sizeof(float);
    float* l4b = (float*)(ws + off); off += P * 32 * 32 * sizeof(float);

    // L0: 512x512, TROWS=16, SX=5, SY=32 -> 15360 waves (1-wave blocks)
    ssim_level_kernel<16, 512, 512, 5><<<15360, 64, 0, stream>>>(
        img1, img2, l1a, l1b, wsum + 2 * (size_t)BOFF[0]);
    // L1: 256x256, TROWS=16, SX=3, SY=16 -> 4608 waves
    ssim_level_kernel<16, 256, 256, 3><<<4608, 64, 0, stream>>>(
        l1a, l1b, l2a, l2b, wsum + 2 * (size_t)BOFF[1]);
    // L2: 128x128, TROWS=16, SX=2, SY=8 -> 1536 waves
    ssim_level_kernel<16, 128, 128, 2><<<1536, 64, 0, stream>>>(
        l2a, l2b, l3a, l3b, wsum + 2 * (size_t)BOFF[2]);
    // L3: 64x64, TROWS=1, SX=1, SY=64 -> 6144 waves
    ssim_level_kernel<1, 64, 64, 1><<<6144, 64, 0, stream>>>(
        l3a, l3b, l4a, l4b, wsum + 2 * (size_t)BOFF[3]);
    // L4: 32x32, TROWS=1, SX=1, SY=32 -> 3072 waves, no pooling
    ssim_level_kernel<1, 32, 32, 1><<<3072, 64, 0, stream>>>(
        l4a, l4b, nullptr, nullptr, wsum + 2 * (size_t)BOFF[4]);

    ssim_final_kernel<<<1, 1024, 0, stream>>>(wsum, out);
}